// Round 6
// baseline (1100.882 us; speedup 1.0000x reference)
//
#include <hip/hip_runtime.h>
#include <hip/hip_bf16.h>

#define B_   64
#define N_   4096
#define NSTEPS 8

__device__ __forceinline__ float fast_sigmoid(float x) {
    return 1.0f / (1.0f + __expf(-x));
}
__device__ __forceinline__ float fast_tanh(float x) {
    // 1 - 2/(exp(2x)+1); correct limits at +/-inf
    return 1.0f - 2.0f / (1.0f + __expf(2.0f * x));
}

// ---------------------------------------------------------------------------
// Kernel 1: UGRNN recurrence. One thread per token (b,n).
// KEY: amdgpu_waves_per_eu(1,2) caps the scheduler's occupancy TARGET at 2
// waves/EU -> 256-VGPR budget the allocator will actually use. R1/R2/R5
// showed __launch_bounds__ min-waves is ignored as a target: compiler chose
// 56-68 VGPRs (max-occupancy heuristic) and spilled 17 MB of scratch
// (WRITE_SIZE 33792 vs 16384 legit). Live set is ~80 floats.
// Writes h transposed: h_t[(n*16+u)*64 + b]  (i-major, b-minor, coalesced).
// ---------------------------------------------------------------------------
__global__
__attribute__((amdgpu_flat_work_group_size(256, 256), amdgpu_waves_per_eu(1, 2)))
void ugrnn_recurrence(
    const float* __restrict__ inputs,
    const float* __restrict__ Wn, const float* __restrict__ Wg,
    const float* __restrict__ Ug, const float* __restrict__ bg,
    const float* __restrict__ Wc, const float* __restrict__ Uc,
    const float* __restrict__ bc, const float* __restrict__ We,
    const float* __restrict__ be, float* __restrict__ h_t)
{
    int t = blockIdx.x * 256 + threadIdx.x;
    int b = t & 63;
    int n = t >> 6;

    // 34 floats per token, 8B-aligned -> 17 float2 gathers
    const float2* ip2 = (const float2*)(inputs + (size_t)(b * N_ + n) * 34);
    float tmp[34];
#pragma unroll
    for (int j = 0; j < 17; ++j) {
        float2 v = ip2[j];
        tmp[2 * j] = v.x;
        tmp[2 * j + 1] = v.y;
    }
    float h0 = tmp[0];
    float e0 = tmp[33];

    // m = neigh @ Wn   (32x16)
    float m[16];
#pragma unroll
    for (int u = 0; u < 16; ++u) m[u] = 0.0f;
#pragma unroll
    for (int k = 0; k < 32; ++k) {
        float xk = tmp[1 + k];
#pragma unroll
        for (int u = 0; u < 16; ++u) m[u] += xk * Wn[k * 16 + u];
    }

    float h[16], e[16];
#pragma unroll
    for (int u = 0; u < 16; ++u) { h[u] = h0; e[u] = e0; }

#pragma unroll 1   // keep I-footprint small (~1.4K inst/step; full unroll would thrash I$)
    for (int step = 0; step < NSTEPS; ++step) {
        float x[16];
#pragma unroll
        for (int u = 0; u < 16; ++u) x[u] = m[u] + e[u];
        // e dead until pass 3 rewrites it

        // ---- pass 1: g = sigmoid(x@Wg + h@Ug + bg) ----
        float g[16];
#pragma unroll
        for (int u = 0; u < 16; ++u) g[u] = bg[u];
#pragma unroll
        for (int k = 0; k < 16; ++k) {
            float xk = x[k], hk = h[k];
#pragma unroll
            for (int u = 0; u < 16; ++u) {
                g[u] += xk * Wg[k * 16 + u];
                g[u] += hk * Ug[k * 16 + u];
            }
        }
#pragma unroll
        for (int u = 0; u < 16; ++u) g[u] = fast_sigmoid(g[u]);

        // ---- pass 2: c = tanh(x@Wc + h@Uc + bc); h = c + g*(h-c) ----
        float c[16];
#pragma unroll
        for (int u = 0; u < 16; ++u) c[u] = bc[u];
#pragma unroll
        for (int k = 0; k < 16; ++k) {
            float xk = x[k], hk = h[k];
#pragma unroll
            for (int u = 0; u < 16; ++u) {
                c[u] += xk * Wc[k * 16 + u];
                c[u] += hk * Uc[k * 16 + u];
            }
        }
#pragma unroll
        for (int u = 0; u < 16; ++u) {
            float cv = fast_tanh(c[u]);
            h[u] = cv + g[u] * (h[u] - cv);
        }

        // ---- pass 3: e = tanh(x@We + be) ----
#pragma unroll
        for (int u = 0; u < 16; ++u) e[u] = be[u];
#pragma unroll
        for (int k = 0; k < 16; ++k) {
            float xk = x[k];
#pragma unroll
            for (int u = 0; u < 16; ++u) e[u] += xk * We[k * 16 + u];
        }
#pragma unroll
        for (int u = 0; u < 16; ++u) e[u] = fast_tanh(e[u]);
    }

    float* hp = h_t + (size_t)(n * 16) * 64 + b;
#pragma unroll
    for (int u = 0; u < 16; ++u) hp[u * 64] = h[u];
}

// ---------------------------------------------------------------------------
// Kernel 2-init: out1[b][j] = b1[j]  (atomic targets start at bias)
// ---------------------------------------------------------------------------
__global__ __launch_bounds__(256) void init_out1(
    const float* __restrict__ b1, float* __restrict__ out1)
{
    int idx = blockIdx.x * 256 + threadIdx.x;   // grid 64 -> 16384
    out1[idx] = b1[idx & 255];
}

// ---------------------------------------------------------------------------
// Kernel 2a: split-K FC1.  out1[b][j] += sum_i h_t[i][b] * W1[i][j]
// grid 512 x 256 (2 blocks/CU -> 2 waves/SIMD to hide W1 HBM latency; R5's
// grid 256 ran 1 wave/SIMD with ~900-cyc load stalls fully exposed).
// Block owns 128 i-rows (2 chunks of 64 staged in LDS). Wave w owns b in
// [16w,16w+16), lane owns cols 4*lane..4*lane+3 (one coalesced float4 W1
// load). acc = float4[16], constant-indexed only. amdgpu_waves_per_eu(1,4):
// 4-wave/EU target -> 128-reg budget (need ~95), no occupancy-chasing spill.
// ---------------------------------------------------------------------------
__global__
__attribute__((amdgpu_flat_work_group_size(256, 256), amdgpu_waves_per_eu(1, 4)))
void fc1_splitk(
    const float* __restrict__ h_t, const float* __restrict__ W1,
    float* __restrict__ out1)
{
    __shared__ float hs[64 * 64];   // 16 KB: hs[i][b]
    int lane = threadIdx.x & 63;
    int wave = threadIdx.x >> 6;
    int b0 = wave * 16;
    int i0 = blockIdx.x * 128;

    float4 acc[16];                 // acc[bb] = cols {4l..4l+3} for row b0+bb
#pragma unroll
    for (int bb = 0; bb < 16; ++bb) acc[bb] = make_float4(0.f, 0.f, 0.f, 0.f);

    for (int s = 0; s < 2; ++s) {
        int ibase = i0 + s * 64;
        __syncthreads();
        const float4* src = (const float4*)(h_t + (size_t)ibase * 64);
        float4* dst = (float4*)hs;
#pragma unroll
        for (int r = 0; r < 4; ++r)
            dst[threadIdx.x + r * 256] = src[threadIdx.x + r * 256];
        __syncthreads();

#pragma unroll 4
        for (int i = 0; i < 64; ++i) {
            // lane's 4 columns: one coalesced 16B load of the W1 row
            float4 wv = ((const float4*)(W1 + (size_t)(ibase + i) * 256))[lane];
            const float4* hp = (const float4*)&hs[i * 64 + b0]; // wave-uniform
#pragma unroll
            for (int c4 = 0; c4 < 4; ++c4) {
                float4 h4 = hp[c4];                  // broadcast ds_read_b128
                acc[c4 * 4 + 0].x += h4.x * wv.x;
                acc[c4 * 4 + 0].y += h4.x * wv.y;
                acc[c4 * 4 + 0].z += h4.x * wv.z;
                acc[c4 * 4 + 0].w += h4.x * wv.w;
                acc[c4 * 4 + 1].x += h4.y * wv.x;
                acc[c4 * 4 + 1].y += h4.y * wv.y;
                acc[c4 * 4 + 1].z += h4.y * wv.z;
                acc[c4 * 4 + 1].w += h4.y * wv.w;
                acc[c4 * 4 + 2].x += h4.z * wv.x;
                acc[c4 * 4 + 2].y += h4.z * wv.y;
                acc[c4 * 4 + 2].z += h4.z * wv.z;
                acc[c4 * 4 + 2].w += h4.z * wv.w;
                acc[c4 * 4 + 3].x += h4.w * wv.x;
                acc[c4 * 4 + 3].y += h4.w * wv.y;
                acc[c4 * 4 + 3].z += h4.w * wv.z;
                acc[c4 * 4 + 3].w += h4.w * wv.w;
            }
        }
    }

    // fully unrolled epilogue: constant indices into acc -> stays in VGPRs
#pragma unroll
    for (int bb = 0; bb < 16; ++bb) {
        float* op = &out1[(b0 + bb) * 256 + 4 * lane];
        atomicAdd(op + 0, acc[bb].x);
        atomicAdd(op + 1, acc[bb].y);
        atomicAdd(op + 2, acc[bb].z);
        atomicAdd(op + 3, acc[bb].w);
    }
}

// ---------------------------------------------------------------------------
// Kernel 2c: tail MLP + softmax. One block per batch row b.
// ---------------------------------------------------------------------------
__global__ __launch_bounds__(64) void mlp_tail(
    const float* __restrict__ out1, const float* __restrict__ W2,
    const float* __restrict__ b2, const float* __restrict__ W3,
    const float* __restrict__ b3, float* __restrict__ out)
{
    __shared__ float x1[256];
    __shared__ float x2[32];
    __shared__ float lg[2];
    int b = blockIdx.x, tid = threadIdx.x;

#pragma unroll
    for (int r = 0; r < 4; ++r) {
        float v = out1[b * 256 + tid * 4 + r];
        x1[tid * 4 + r] = fmaxf(v, 0.0f);
    }
    __syncthreads();

    if (tid < 32) {
        float s = b2[tid];
#pragma unroll 8
        for (int k = 0; k < 256; ++k) s += x1[k] * W2[k * 32 + tid];
        x2[tid] = fmaxf(s, 0.0f);
    }
    __syncthreads();

    if (tid < 2) {
        float s = b3[tid];
#pragma unroll
        for (int k = 0; k < 32; ++k) s += x2[k] * W3[k * 2 + tid];
        lg[tid] = s;
    }
    __syncthreads();

    if (tid == 0) {
        float mx = fmaxf(lg[0], lg[1]);
        float e0 = __expf(lg[0] - mx), e1 = __expf(lg[1] - mx);
        float inv = 1.0f / (e0 + e1);
        out[b * 2 + 0] = e0 * inv;
        out[b * 2 + 1] = e1 * inv;
    }
}

// ---------------------------------------------------------------------------
extern "C" void kernel_launch(void* const* d_in, const int* in_sizes, int n_in,
                              void* d_out, int out_size, void* d_ws, size_t ws_size,
                              hipStream_t stream) {
    const float* inputs = (const float*)d_in[0];
    const float* Wn = (const float*)d_in[1];
    const float* Wg = (const float*)d_in[2];
    const float* Ug = (const float*)d_in[3];
    const float* bg = (const float*)d_in[4];
    const float* Wc = (const float*)d_in[5];
    const float* Uc = (const float*)d_in[6];
    const float* bc = (const float*)d_in[7];
    const float* We = (const float*)d_in[8];
    const float* be = (const float*)d_in[9];
    const float* W1 = (const float*)d_in[10];
    const float* b1 = (const float*)d_in[11];
    const float* W2 = (const float*)d_in[12];
    const float* b2 = (const float*)d_in[13];
    const float* W3 = (const float*)d_in[14];
    const float* b3 = (const float*)d_in[15];
    float* out = (float*)d_out;

    // workspace layout
    float* h_t  = (float*)d_ws;                                   // 65536*64 f32 = 16 MB
    float* out1 = (float*)((char*)d_ws + (size_t)65536 * 64 * 4); // 64*256 f32 = 64 KB

    ugrnn_recurrence<<<1024, 256, 0, stream>>>(inputs, Wn, Wg, Ug, bg, Wc, Uc, bc,
                                               We, be, h_t);
    init_out1<<<64, 256, 0, stream>>>(b1, out1);
    fc1_splitk<<<512, 256, 0, stream>>>(h_t, W1, out1);
    mlp_tail<<<64, 64, 0, stream>>>(out1, W2, b2, W3, b3, out);
}

// Round 7
// 294.750 us; speedup vs baseline: 3.7350x; 3.7350x over previous
//
#include <hip/hip_runtime.h>
#include <hip/hip_bf16.h>

typedef _Float16 half8_t __attribute__((ext_vector_type(8)));
typedef _Float16 half4_t __attribute__((ext_vector_type(4)));
typedef float    f32x4  __attribute__((ext_vector_type(4)));

#define MFMA16(a, b, c) __builtin_amdgcn_mfma_f32_16x16x32_f16((a), (b), (c), 0, 0, 0)

// ---------------------------------------------------------------------------
// Kernel 1: UGRNN recurrence on the MFMA pipe. One wave = 16 tokens
// (b fixed, n0..n0+15). Fused A = [x | h] (K=32), B-frags [Wg;Ug], [Wc;Uc],
// [We;0] live in VGPRs (loaded once). Per step: 3 MFMAs + LDS C->A layout
// round-trip (2 ds_write_b64 + 8 ds_read_u16, per-wave slice, wave-sync).
// State h,e stays fp32 (C-layout) across steps -> no f16 error accumulation.
// Layouts (gfx950 16x16x32): A[m=lane&15][k=8q+i], B[k=8q+i][n=lane&15],
// C/D[row=4q+r][col=lane&15].
// ---------------------------------------------------------------------------
__global__
__attribute__((amdgpu_flat_work_group_size(256, 256), amdgpu_waves_per_eu(1, 3)))
void ugrnn_mfma(
    const float* __restrict__ inputs,
    const float* __restrict__ Wn, const float* __restrict__ Wg,
    const float* __restrict__ Ug, const float* __restrict__ bg,
    const float* __restrict__ Wc, const float* __restrict__ Uc,
    const float* __restrict__ bc, const float* __restrict__ We,
    const float* __restrict__ be, _Float16* __restrict__ h_t)
{
    __shared__ float     raw[4][16 * 34];   // [wave][t*34 + j] staged inputs
    __shared__ _Float16  T[4][32][20];      // [wave][k][t], rows padded to 20

    const int wave = threadIdx.x >> 6;
    const int lane = threadIdx.x & 63;
    const int t16  = lane & 15;
    const int q    = lane >> 4;

    const int tile = blockIdx.x * 4 + wave;   // 0..16383
    const int b    = tile >> 8;               // token batch row
    const int n0   = (tile & 255) << 4;       // first of 16 consecutive n

    // ---- stage 16 tokens x 34 floats (contiguous 544 floats, coalesced) ----
    const float* gsrc = inputs + ((size_t)b * 4096 + n0) * 34;
    float* rw = raw[wave];
#pragma unroll
    for (int r = 0; r < 9; ++r) {
        int idx = r * 64 + lane;
        if (idx < 544) rw[idx] = gsrc[idx];
    }

    // ---- one-time B fragments (f16, in VGPRs) ----
    half8_t Bn, Bg8, Bc8, Be8;
#pragma unroll
    for (int i = 0; i < 8; ++i) {
        int kk = q * 8 + i;                 // 0..31
        Bn[i] = (_Float16)Wn[kk * 16 + t16];
        float gv = (kk < 16) ? Wg[kk * 16 + t16] : Ug[(kk - 16) * 16 + t16];
        float cv = (kk < 16) ? Wc[kk * 16 + t16] : Uc[(kk - 16) * 16 + t16];
        float ev = (kk < 16) ? We[kk * 16 + t16] : 0.0f;
        Bg8[i] = (_Float16)gv;
        Bc8[i] = (_Float16)cv;
        Be8[i] = (_Float16)ev;
    }
    float bgv = bg[t16], bcv = bc[t16], bev = be[t16];
    f32x4 bgC = {bgv, bgv, bgv, bgv};
    f32x4 bcC = {bcv, bcv, bcv, bcv};
    f32x4 beC = {bev, bev, bev, bev};

    // wait for staging (wave-local LDS; DS ops in-order per wave)
    asm volatile("s_waitcnt lgkmcnt(0)" ::: "memory");

    // ---- m = neigh(16x32) @ Wn(32x16), one K=32 MFMA ----
    half8_t An;
#pragma unroll
    for (int i = 0; i < 8; ++i)
        An[i] = (_Float16)rw[t16 * 34 + 1 + q * 8 + i];
    f32x4 zc = {0.f, 0.f, 0.f, 0.f};
    f32x4 m = MFMA16(An, Bn, zc);

    // ---- init h, e in C-layout: lane holds tokens 4q..4q+3 at unit t16 ----
    f32x4 h, e;
#pragma unroll
    for (int r = 0; r < 4; ++r) {
        h[r] = rw[(4 * q + r) * 34 + 0];    // h0 broadcast over units
        e[r] = rw[(4 * q + r) * 34 + 33];   // e0 broadcast over units
    }

    _Float16* Tw = &T[wave][0][0];          // row stride 20 halves

#pragma unroll 1
    for (int step = 0; step < 8; ++step) {
        f32x4 x = m + e;

        // C-layout -> transposed LDS tile: x[token][unit] -> T[unit][token]
        half4_t xp, hp;
#pragma unroll
        for (int r = 0; r < 4; ++r) { xp[r] = (_Float16)x[r]; hp[r] = (_Float16)h[r]; }
        *(half4_t*)&Tw[t16 * 20 + 4 * q]        = xp;   // rows 0-15: x by unit
        *(half4_t*)&Tw[(16 + t16) * 20 + 4 * q] = hp;   // rows 16-31: h by unit

        asm volatile("s_waitcnt lgkmcnt(0)" ::: "memory");

        // fused A = [x | h]: lane reads k=8q..8q+7 at token t16
        half8_t A;
#pragma unroll
        for (int i = 0; i < 8; ++i)
            A[i] = Tw[(q * 8 + i) * 20 + t16];

        f32x4 gp = MFMA16(A, Bg8, bgC);
        f32x4 cp = MFMA16(A, Bc8, bcC);
        f32x4 ep = MFMA16(A, Be8, beC);

#pragma unroll
        for (int r = 0; r < 4; ++r) {
            float gv = __builtin_amdgcn_rcpf(1.0f + __expf(-gp[r]));
            float cv = 1.0f - 2.0f * __builtin_amdgcn_rcpf(1.0f + __expf(2.0f * cp[r]));
            h[r] = cv + gv * (h[r] - cv);
            e[r] = 1.0f - 2.0f * __builtin_amdgcn_rcpf(1.0f + __expf(2.0f * ep[r]));
        }
    }

    // ---- write h as f16: h_t[b][(n0+4q+r)*16 + t16] ----
    _Float16* hd = h_t + (size_t)b * 65536 + (size_t)n0 * 16 + t16;
#pragma unroll
    for (int r = 0; r < 4; ++r)
        hd[(4 * q + r) * 16] = (_Float16)h[r];
}

// ---------------------------------------------------------------------------
// Kernel 2-init: out1[b][j] = b1[j]  (atomic targets start at bias)
// ---------------------------------------------------------------------------
__global__ __launch_bounds__(256) void init_out1(
    const float* __restrict__ b1, float* __restrict__ out1)
{
    int idx = blockIdx.x * 256 + threadIdx.x;   // grid 64 -> 16384
    out1[idx] = b1[idx & 255];
}

// ---------------------------------------------------------------------------
// Kernel 2a: FC1 via MFMA. out1[b][j] += sum_i h[b][i] * W1[i][j].
// Grid 512 = 128 K-chunks (512 i each) x 4 j-panels (64 cols each).
// Block stages h-chunk (64 b x 512 i, f16, 65 KB LDS); 4 waves split K
// (128 i each), each computing the full 64b x 64j panel -> 16 C-frags.
// B-frags streamed from W1 global (64B segments, HBM-bound by design).
// Block-level LDS reduction over the 4 waves, then 4096 atomics/block
// (2.1M total, 4x fewer than wave-direct).
// ---------------------------------------------------------------------------
#define KCH 512
__global__
__attribute__((amdgpu_flat_work_group_size(256, 256), amdgpu_waves_per_eu(1, 2)))
void fc1_mfma(const _Float16* __restrict__ h_t, const float* __restrict__ W1,
              float* __restrict__ out1)
{
    __shared__ _Float16 hs[64][KCH + 8];    // 66560 B; pad 8 halves
    const int tid  = threadIdx.x;
    const int wave = tid >> 6;
    const int lane = tid & 63;
    const int t16  = lane & 15;
    const int q    = lane >> 4;
    const int kblk = blockIdx.x >> 2;       // 0..127
    const int jpan = blockIdx.x & 3;        // 0..3
    const int i0   = kblk * KCH;
    const int j0   = jpan * 64;

    // ---- stage h chunk: all 64 b rows, i in [i0, i0+512) ----
    {
        int b  = tid >> 2;
        int c0 = (tid & 3) * 128;
#pragma unroll
        for (int r = 0; r < 16; ++r) {
            int c = c0 + r * 8;
            *(half8_t*)&hs[b][c] =
                *(const half8_t*)(h_t + (size_t)b * 65536 + i0 + c);
        }
    }
    __syncthreads();

    f32x4 acc[4][4];
#pragma unroll
    for (int mt = 0; mt < 4; ++mt)
#pragma unroll
        for (int nt = 0; nt < 4; ++nt)
            acc[mt][nt] = (f32x4){0.f, 0.f, 0.f, 0.f};

    const int iw = wave * 128;              // wave's K-sub-chunk
    const float* Wbase = W1 + (size_t)(i0 + iw) * 256 + j0;

#pragma unroll 1
    for (int kc = 0; kc < 4; ++kc) {        // 4 x K=32
        half8_t A[4];
#pragma unroll
        for (int mt = 0; mt < 4; ++mt)
            A[mt] = *(const half8_t*)&hs[mt * 16 + t16][iw + kc * 32 + q * 8];

#pragma unroll
        for (int nt = 0; nt < 4; ++nt) {
            half8_t Bf;
#pragma unroll
            for (int i = 0; i < 8; ++i) {
                int krow = kc * 32 + q * 8 + i;
                Bf[i] = (_Float16)Wbase[(size_t)krow * 256 + nt * 16 + t16];
            }
#pragma unroll
            for (int mt = 0; mt < 4; ++mt)
                acc[mt][nt] = MFMA16(A[mt], Bf, acc[mt][nt]);
        }
    }

    // ---- block reduction across the 4 waves (reuse hs as fp32 scratch) ----
    __syncthreads();                        // hs reads done
    float* red = (float*)&hs[0][0];         // 4 waves x 4096 fp32 = 64 KB
#pragma unroll
    for (int mt = 0; mt < 4; ++mt)
#pragma unroll
        for (int nt = 0; nt < 4; ++nt)
#pragma unroll
            for (int r = 0; r < 4; ++r)
                red[wave * 4096 + (mt * 16 + 4 * q + r) * 64 + nt * 16 + t16] =
                    acc[mt][nt][r];
    __syncthreads();

#pragma unroll
    for (int r = 0; r < 16; ++r) {
        int idx = tid * 16 + r;             // 0..4095: b = idx>>6, jc = idx&63
        float s = red[idx] + red[4096 + idx] + red[8192 + idx] + red[12288 + idx];
        atomicAdd(&out1[(idx >> 6) * 256 + j0 + (idx & 63)], s);
    }
}

// ---------------------------------------------------------------------------
// Kernel 2c: tail MLP + softmax. One block per batch row b.
// ---------------------------------------------------------------------------
__global__ __launch_bounds__(64) void mlp_tail(
    const float* __restrict__ out1, const float* __restrict__ W2,
    const float* __restrict__ b2, const float* __restrict__ W3,
    const float* __restrict__ b3, float* __restrict__ out)
{
    __shared__ float x1[256];
    __shared__ float x2[32];
    __shared__ float lg[2];
    int b = blockIdx.x, tid = threadIdx.x;

#pragma unroll
    for (int r = 0; r < 4; ++r) {
        float v = out1[b * 256 + tid * 4 + r];
        x1[tid * 4 + r] = fmaxf(v, 0.0f);
    }
    __syncthreads();

    if (tid < 32) {
        float s = b2[tid];
#pragma unroll 8
        for (int k = 0; k < 256; ++k) s += x1[k] * W2[k * 32 + tid];
        x2[tid] = fmaxf(s, 0.0f);
    }
    __syncthreads();

    if (tid < 2) {
        float s = b3[tid];
#pragma unroll
        for (int k = 0; k < 32; ++k) s += x2[k] * W3[k * 2 + tid];
        lg[tid] = s;
    }
    __syncthreads();

    if (tid == 0) {
        float mx = fmaxf(lg[0], lg[1]);
        float e0 = __expf(lg[0] - mx), e1 = __expf(lg[1] - mx);
        float inv = 1.0f / (e0 + e1);
        out[b * 2 + 0] = e0 * inv;
        out[b * 2 + 1] = e1 * inv;
    }
}

// ---------------------------------------------------------------------------
extern "C" void kernel_launch(void* const* d_in, const int* in_sizes, int n_in,
                              void* d_out, int out_size, void* d_ws, size_t ws_size,
                              hipStream_t stream) {
    const float* inputs = (const float*)d_in[0];
    const float* Wn = (const float*)d_in[1];
    const float* Wg = (const float*)d_in[2];
    const float* Ug = (const float*)d_in[3];
    const float* bg = (const float*)d_in[4];
    const float* Wc = (const float*)d_in[5];
    const float* Uc = (const float*)d_in[6];
    const float* bc = (const float*)d_in[7];
    const float* We = (const float*)d_in[8];
    const float* be = (const float*)d_in[9];
    const float* W1 = (const float*)d_in[10];
    const float* b1 = (const float*)d_in[11];
    const float* W2 = (const float*)d_in[12];
    const float* b2 = (const float*)d_in[13];
    const float* W3 = (const float*)d_in[14];
    const float* b3 = (const float*)d_in[15];
    float* out = (float*)d_out;

    // workspace: h_t f16 [64][65536] = 8 MB, then out1 fp32 64x256
    _Float16* h_t = (_Float16*)d_ws;
    float* out1 = (float*)((char*)d_ws + (size_t)64 * 65536 * 2);

    ugrnn_mfma<<<4096, 256, 0, stream>>>(inputs, Wn, Wg, Ug, bg, Wc, Uc, bc,
                                         We, be, h_t);
    init_out1<<<64, 256, 0, stream>>>(b1, out1);
    fc1_mfma<<<512, 256, 0, stream>>>(h_t, W1, out1);
    mlp_tail<<<64, 64, 0, stream>>>(out1, W2, b2, W3, b3, out);
}

// Round 8
// 238.718 us; speedup vs baseline: 4.6116x; 1.2347x over previous
//
#include <hip/hip_runtime.h>
#include <hip/hip_bf16.h>

typedef _Float16 half8_t __attribute__((ext_vector_type(8)));
typedef _Float16 half4_t __attribute__((ext_vector_type(4)));
typedef float    f32x4  __attribute__((ext_vector_type(4)));

#define MFMA16(a, b, c) __builtin_amdgcn_mfma_f32_16x16x32_f16((a), (b), (c), 0, 0, 0)

// ---------------------------------------------------------------------------
// Kernel 1: UGRNN recurrence on MFMA. One wave = TWO 16-token tiles (32
// tokens, b fixed): two independent LDS-roundtrip->MFMA->activation chains
// per step interleave to hide the lgkmcnt waits. B-frags [Wg;Ug],[Wc;Uc],
// [We;0] in VGPRs (loaded once, amortized over 2 tiles). h,e state fp32.
// Last step's e (dead) skipped.
// Layouts (16x16x32): A[m=t16][k=8q+i], B[k=8q+i][n=t16], C/D[4q+r][t16].
// ---------------------------------------------------------------------------
__global__
__attribute__((amdgpu_flat_work_group_size(256, 256), amdgpu_waves_per_eu(1, 3)))
void ugrnn_mfma(
    const float* __restrict__ inputs,
    const float* __restrict__ Wn, const float* __restrict__ Wg,
    const float* __restrict__ Ug, const float* __restrict__ bg,
    const float* __restrict__ Wc, const float* __restrict__ Uc,
    const float* __restrict__ bc, const float* __restrict__ We,
    const float* __restrict__ be, _Float16* __restrict__ h_t)
{
    __shared__ float     raw[4][2 * 544];     // [wave][tile*544 + t*34 + j]
    __shared__ _Float16  T[4][2][32][20];     // [wave][tile][k][t] pad 20

    const int wave = threadIdx.x >> 6;
    const int lane = threadIdx.x & 63;
    const int t16  = lane & 15;
    const int q    = lane >> 4;

    const int pair = blockIdx.x * 4 + wave;   // 0..8191
    const int b    = pair >> 7;               // 128 pairs (4096 tokens) per b
    const int n0   = (pair & 127) << 5;       // 32 consecutive n

    // ---- stage 2x16 tokens x 34 floats (1088 contiguous, coalesced) ----
    const float* gsrc = inputs + ((size_t)b * 4096 + n0) * 34;
    float* rw = raw[wave];
#pragma unroll
    for (int r = 0; r < 17; ++r) rw[r * 64 + lane] = gsrc[r * 64 + lane];

    // ---- one-time B fragments (f16, VGPRs) ----
    half8_t Bn, Bg8, Bc8, Be8;
#pragma unroll
    for (int i = 0; i < 8; ++i) {
        int kk = q * 8 + i;                   // 0..31
        Bn[i] = (_Float16)Wn[kk * 16 + t16];
        float gv = (kk < 16) ? Wg[kk * 16 + t16] : Ug[(kk - 16) * 16 + t16];
        float cv = (kk < 16) ? Wc[kk * 16 + t16] : Uc[(kk - 16) * 16 + t16];
        float ev = (kk < 16) ? We[kk * 16 + t16] : 0.0f;
        Bg8[i] = (_Float16)gv;
        Bc8[i] = (_Float16)cv;
        Be8[i] = (_Float16)ev;
    }
    float bgv = bg[t16], bcv = bc[t16], bev = be[t16];
    f32x4 bgC = {bgv, bgv, bgv, bgv};
    f32x4 bcC = {bcv, bcv, bcv, bcv};
    f32x4 beC = {bev, bev, bev, bev};

    asm volatile("s_waitcnt lgkmcnt(0)" ::: "memory");  // staging ds_writes done

    // ---- m = neigh @ Wn per tile; h,e init (C-layout) ----
    f32x4 m[2], h[2], e[2];
    f32x4 zc = {0.f, 0.f, 0.f, 0.f};
#pragma unroll
    for (int u2 = 0; u2 < 2; ++u2) {
        const float* rt = rw + u2 * 544;
        half8_t An;
#pragma unroll
        for (int i = 0; i < 8; ++i)
            An[i] = (_Float16)rt[t16 * 34 + 1 + q * 8 + i];
        m[u2] = MFMA16(An, Bn, zc);
#pragma unroll
        for (int r = 0; r < 4; ++r) {
            h[u2][r] = rt[(4 * q + r) * 34 + 0];
            e[u2][r] = rt[(4 * q + r) * 34 + 33];
        }
    }

#pragma unroll 1
    for (int step = 0; step < 8; ++step) {
        // ---- C->A transpose via LDS, both tiles, one wait ----
#pragma unroll
        for (int u2 = 0; u2 < 2; ++u2) {
            f32x4 x = m[u2] + e[u2];
            half4_t xp, hp;
#pragma unroll
            for (int r = 0; r < 4; ++r) { xp[r] = (_Float16)x[r]; hp[r] = (_Float16)h[u2][r]; }
            _Float16* Tw = &T[wave][u2][0][0];
            *(half4_t*)&Tw[t16 * 20 + 4 * q]        = xp;   // rows 0-15: x
            *(half4_t*)&Tw[(16 + t16) * 20 + 4 * q] = hp;   // rows 16-31: h
        }
        asm volatile("s_waitcnt lgkmcnt(0)" ::: "memory");

        f32x4 gp[2], cp[2], ep[2];
#pragma unroll
        for (int u2 = 0; u2 < 2; ++u2) {
            const _Float16* Tw = &T[wave][u2][0][0];
            half8_t A;
#pragma unroll
            for (int i = 0; i < 8; ++i)
                A[i] = Tw[(q * 8 + i) * 20 + t16];
            gp[u2] = MFMA16(A, Bg8, bgC);
            cp[u2] = MFMA16(A, Bc8, bcC);
            if (step < 7) ep[u2] = MFMA16(A, Be8, beC);
        }

#pragma unroll
        for (int u2 = 0; u2 < 2; ++u2) {
#pragma unroll
            for (int r = 0; r < 4; ++r) {
                float gv = __builtin_amdgcn_rcpf(1.0f + __expf(-gp[u2][r]));
                float cv = 1.0f - 2.0f * __builtin_amdgcn_rcpf(1.0f + __expf(2.0f * cp[u2][r]));
                h[u2][r] = cv + gv * (h[u2][r] - cv);
                if (step < 7)
                    e[u2][r] = 1.0f - 2.0f * __builtin_amdgcn_rcpf(1.0f + __expf(2.0f * ep[u2][r]));
            }
        }
    }

    // ---- h_t[b][(n0 + u2*16 + 4q+r)*16 + t16] (f16) ----
    _Float16* hd = h_t + (size_t)b * 65536 + (size_t)n0 * 16 + t16;
#pragma unroll
    for (int u2 = 0; u2 < 2; ++u2)
#pragma unroll
        for (int r = 0; r < 4; ++r)
            hd[(u2 * 16 + 4 * q + r) * 16] = (_Float16)h[u2][r];
}

// ---------------------------------------------------------------------------
// Kernel 2: FC1 partial GEMM, atomic-free. Grid 256: block = K-chunk of 256
// (two 128-row halves). W1 half staged ROW-MAJOR f16 in LDS (coalesced
// float4 loads, b64 stores) — B-frags built with 8x ds_read_u16 (row stride
// 270 spreads banks). A-frags read 16B-contiguous from h_t global. Wave w
// owns j-panel [64w,64w+64): acc 4x4 frags. Block writes its 64x256 f16
// partial to ws — no atomics (R7: atomics cost 64 MB of HBM RMW writes).
// ---------------------------------------------------------------------------
__global__
__attribute__((amdgpu_flat_work_group_size(256, 256), amdgpu_waves_per_eu(1, 2)))
void fc1_mfma(const _Float16* __restrict__ h_t, const float* __restrict__ W1,
              _Float16* __restrict__ partials)
{
    __shared__ _Float16 w1s[128][270];        // 69120 B
    const int tid  = threadIdx.x;
    const int wave = tid >> 6;
    const int lane = tid & 63;
    const int t16  = lane & 15;
    const int q    = lane >> 4;
    const int i0   = blockIdx.x * 256;

    f32x4 acc[4][4];
#pragma unroll
    for (int mt = 0; mt < 4; ++mt)
#pragma unroll
        for (int nt = 0; nt < 4; ++nt)
            acc[mt][nt] = (f32x4){0.f, 0.f, 0.f, 0.f};

#pragma unroll 1
    for (int half = 0; half < 2; ++half) {
        const int ib = i0 + half * 128;
        __syncthreads();                      // prior reads done before overwrite
        // ---- stage 128 rows x 256 cols fp32 -> f16, row-major ----
#pragma unroll
        for (int it = 0; it < 32; ++it) {
            int k  = it * 4 + wave;           // per-wave uniform row
            int j4 = lane * 4;
            float4 w = *(const float4*)&W1[(size_t)(ib + k) * 256 + j4];
            half4_t hv;
            hv[0] = (_Float16)w.x; hv[1] = (_Float16)w.y;
            hv[2] = (_Float16)w.z; hv[3] = (_Float16)w.w;
            *(half4_t*)&w1s[k][j4] = hv;
        }
        __syncthreads();

        // ---- 4 K=32 slices ----
#pragma unroll
        for (int ks = 0; ks < 4; ++ks) {
            half8_t A[4];
#pragma unroll
            for (int mt = 0; mt < 4; ++mt)
                A[mt] = *(const half8_t*)(h_t + (size_t)(mt * 16 + t16) * 65536
                                          + ib + ks * 32 + q * 8);
#pragma unroll
            for (int nt = 0; nt < 4; ++nt) {
                int j = (wave * 4 + nt) * 16 + t16;
                half8_t Bf;
#pragma unroll
                for (int i = 0; i < 8; ++i)
                    Bf[i] = w1s[ks * 32 + q * 8 + i][j];
#pragma unroll
                for (int mt = 0; mt < 4; ++mt)
                    acc[mt][nt] = MFMA16(A[mt], Bf, acc[mt][nt]);
            }
        }
    }

    // ---- write 64x256 f16 partial (disjoint per wave: j-panel) ----
    _Float16* pb = partials + (size_t)blockIdx.x * 16384;
#pragma unroll
    for (int mt = 0; mt < 4; ++mt)
#pragma unroll
        for (int nt = 0; nt < 4; ++nt)
#pragma unroll
            for (int r = 0; r < 4; ++r)
                pb[(mt * 16 + 4 * q + r) * 256 + (wave * 4 + nt) * 16 + t16] =
                    (_Float16)acc[mt][nt][r];
}

// ---------------------------------------------------------------------------
// Kernel 3: fused partial-reduce + bias + tail MLP + softmax.
// One block (256 thr) per batch row b; thread j sums 256 f16 partials
// (coalesced 512B rows), then relu -> 256x32 -> relu -> 32x2 -> softmax.
// ---------------------------------------------------------------------------
__global__ __launch_bounds__(256) void mlp_tail(
    const _Float16* __restrict__ partials, const float* __restrict__ b1,
    const float* __restrict__ W2, const float* __restrict__ b2,
    const float* __restrict__ W3, const float* __restrict__ b3,
    float* __restrict__ out)
{
    __shared__ float x1[256];
    __shared__ float x2[32];
    __shared__ float lg[2];
    const int b = blockIdx.x, j = threadIdx.x;

    const _Float16* p = partials + (size_t)b * 256 + j;
    float s0 = 0.f, s1 = 0.f, s2 = 0.f, s3 = 0.f;
#pragma unroll 8
    for (int k = 0; k < 256; k += 4) {
        s0 += (float)p[(size_t)(k + 0) * 16384];
        s1 += (float)p[(size_t)(k + 1) * 16384];
        s2 += (float)p[(size_t)(k + 2) * 16384];
        s3 += (float)p[(size_t)(k + 3) * 16384];
    }
    x1[j] = fmaxf(b1[j] + s0 + s1 + s2 + s3, 0.0f);
    __syncthreads();

    if (j < 32) {
        float s = b2[j];
#pragma unroll 8
        for (int k = 0; k < 256; ++k) s += x1[k] * W2[k * 32 + j];
        x2[j] = fmaxf(s, 0.0f);
    }
    __syncthreads();

    if (j < 2) {
        float s = b3[j];
#pragma unroll
        for (int k = 0; k < 32; ++k) s += x2[k] * W3[k * 2 + j];
        lg[j] = s;
    }
    __syncthreads();

    if (j == 0) {
        float mx = fmaxf(lg[0], lg[1]);
        float e0 = __expf(lg[0] - mx), e1 = __expf(lg[1] - mx);
        float inv = 1.0f / (e0 + e1);
        out[b * 2 + 0] = e0 * inv;
        out[b * 2 + 1] = e1 * inv;
    }
}

// ---------------------------------------------------------------------------
extern "C" void kernel_launch(void* const* d_in, const int* in_sizes, int n_in,
                              void* d_out, int out_size, void* d_ws, size_t ws_size,
                              hipStream_t stream) {
    const float* inputs = (const float*)d_in[0];
    const float* Wn = (const float*)d_in[1];
    const float* Wg = (const float*)d_in[2];
    const float* Ug = (const float*)d_in[3];
    const float* bg = (const float*)d_in[4];
    const float* Wc = (const float*)d_in[5];
    const float* Uc = (const float*)d_in[6];
    const float* bc = (const float*)d_in[7];
    const float* We = (const float*)d_in[8];
    const float* be = (const float*)d_in[9];
    const float* W1 = (const float*)d_in[10];
    const float* b1 = (const float*)d_in[11];
    const float* W2 = (const float*)d_in[12];
    const float* b2 = (const float*)d_in[13];
    const float* W3 = (const float*)d_in[14];
    const float* b3 = (const float*)d_in[15];
    float* out = (float*)d_out;

    // ws: h_t f16 [64][65536] = 8 MB; partials f16 [256][64][256] = 8 MB
    _Float16* h_t      = (_Float16*)d_ws;
    _Float16* partials = (_Float16*)((char*)d_ws + (size_t)64 * 65536 * 2);

    ugrnn_mfma<<<2048, 256, 0, stream>>>(inputs, Wn, Wg, Ug, bg, Wc, Uc, bc,
                                         We, be, h_t);
    fc1_mfma<<<256, 256, 0, stream>>>(h_t, W1, partials);
    mlp_tail<<<64, 256, 0, stream>>>(partials, b1, W2, b2, W3, b3, out);
}

// Round 9
// 213.024 us; speedup vs baseline: 5.1679x; 1.1206x over previous
//
#include <hip/hip_runtime.h>
#include <hip/hip_bf16.h>

typedef _Float16 half8_t __attribute__((ext_vector_type(8)));
typedef _Float16 half4_t __attribute__((ext_vector_type(4)));
typedef float    f32x4  __attribute__((ext_vector_type(4)));

#define MFMA16(a, b, c) __builtin_amdgcn_mfma_f32_16x16x32_f16((a), (b), (c), 0, 0, 0)

// async global->LDS DMA, 16B per lane: LDS dst = base + lane*16 (HW rule)
__device__ __forceinline__ void load_lds16(const void* g, void* l) {
    __builtin_amdgcn_global_load_lds(
        (const __attribute__((address_space(1))) unsigned int*)g,
        (__attribute__((address_space(3))) unsigned int*)l, 16, 0, 0);
}

// ---------------------------------------------------------------------------
// Kernel 1: UGRNN recurrence on MFMA. One wave = TWO 16-token tiles (32
// tokens, b fixed): two independent LDS-roundtrip->MFMA->activation chains
// per step interleave to hide the lgkmcnt waits. B-frags [Wg;Ug],[Wc;Uc],
// [We;0] in VGPRs (loaded once). h,e state fp32. (unchanged from R8)
// Layouts (16x16x32): A[m=t16][k=8q+i], B[k=8q+i][n=t16], C/D[4q+r][t16].
// ---------------------------------------------------------------------------
__global__
__attribute__((amdgpu_flat_work_group_size(256, 256), amdgpu_waves_per_eu(1, 3)))
void ugrnn_mfma(
    const float* __restrict__ inputs,
    const float* __restrict__ Wn, const float* __restrict__ Wg,
    const float* __restrict__ Ug, const float* __restrict__ bg,
    const float* __restrict__ Wc, const float* __restrict__ Uc,
    const float* __restrict__ bc, const float* __restrict__ We,
    const float* __restrict__ be, _Float16* __restrict__ h_t)
{
    __shared__ float     raw[4][2 * 544];
    __shared__ _Float16  T[4][2][32][20];

    const int wave = threadIdx.x >> 6;
    const int lane = threadIdx.x & 63;
    const int t16  = lane & 15;
    const int q    = lane >> 4;

    const int pair = blockIdx.x * 4 + wave;
    const int b    = pair >> 7;
    const int n0   = (pair & 127) << 5;

    const float* gsrc = inputs + ((size_t)b * 4096 + n0) * 34;
    float* rw = raw[wave];
#pragma unroll
    for (int r = 0; r < 17; ++r) rw[r * 64 + lane] = gsrc[r * 64 + lane];

    half8_t Bn, Bg8, Bc8, Be8;
#pragma unroll
    for (int i = 0; i < 8; ++i) {
        int kk = q * 8 + i;
        Bn[i] = (_Float16)Wn[kk * 16 + t16];
        float gv = (kk < 16) ? Wg[kk * 16 + t16] : Ug[(kk - 16) * 16 + t16];
        float cv = (kk < 16) ? Wc[kk * 16 + t16] : Uc[(kk - 16) * 16 + t16];
        float ev = (kk < 16) ? We[kk * 16 + t16] : 0.0f;
        Bg8[i] = (_Float16)gv;
        Bc8[i] = (_Float16)cv;
        Be8[i] = (_Float16)ev;
    }
    float bgv = bg[t16], bcv = bc[t16], bev = be[t16];
    f32x4 bgC = {bgv, bgv, bgv, bgv};
    f32x4 bcC = {bcv, bcv, bcv, bcv};
    f32x4 beC = {bev, bev, bev, bev};

    asm volatile("s_waitcnt lgkmcnt(0)" ::: "memory");

    f32x4 m[2], h[2], e[2];
    f32x4 zc = {0.f, 0.f, 0.f, 0.f};
#pragma unroll
    for (int u2 = 0; u2 < 2; ++u2) {
        const float* rt = rw + u2 * 544;
        half8_t An;
#pragma unroll
        for (int i = 0; i < 8; ++i)
            An[i] = (_Float16)rt[t16 * 34 + 1 + q * 8 + i];
        m[u2] = MFMA16(An, Bn, zc);
#pragma unroll
        for (int r = 0; r < 4; ++r) {
            h[u2][r] = rt[(4 * q + r) * 34 + 0];
            e[u2][r] = rt[(4 * q + r) * 34 + 33];
        }
    }

#pragma unroll 1
    for (int step = 0; step < 8; ++step) {
#pragma unroll
        for (int u2 = 0; u2 < 2; ++u2) {
            f32x4 x = m[u2] + e[u2];
            half4_t xp, hp;
#pragma unroll
            for (int r = 0; r < 4; ++r) { xp[r] = (_Float16)x[r]; hp[r] = (_Float16)h[u2][r]; }
            _Float16* Tw = &T[wave][u2][0][0];
            *(half4_t*)&Tw[t16 * 20 + 4 * q]        = xp;
            *(half4_t*)&Tw[(16 + t16) * 20 + 4 * q] = hp;
        }
        asm volatile("s_waitcnt lgkmcnt(0)" ::: "memory");

        f32x4 gp[2], cp[2], ep[2];
#pragma unroll
        for (int u2 = 0; u2 < 2; ++u2) {
            const _Float16* Tw = &T[wave][u2][0][0];
            half8_t A;
#pragma unroll
            for (int i = 0; i < 8; ++i)
                A[i] = Tw[(q * 8 + i) * 20 + t16];
            gp[u2] = MFMA16(A, Bg8, bgC);
            cp[u2] = MFMA16(A, Bc8, bcC);
            if (step < 7) ep[u2] = MFMA16(A, Be8, beC);
        }

#pragma unroll
        for (int u2 = 0; u2 < 2; ++u2) {
#pragma unroll
            for (int r = 0; r < 4; ++r) {
                float gv = __builtin_amdgcn_rcpf(1.0f + __expf(-gp[u2][r]));
                float cv = 1.0f - 2.0f * __builtin_amdgcn_rcpf(1.0f + __expf(2.0f * cp[u2][r]));
                h[u2][r] = cv + gv * (h[u2][r] - cv);
                if (step < 7)
                    e[u2][r] = 1.0f - 2.0f * __builtin_amdgcn_rcpf(1.0f + __expf(2.0f * ep[u2][r]));
            }
        }
    }

    _Float16* hd = h_t + (size_t)b * 65536 + (size_t)n0 * 16 + t16;
#pragma unroll
    for (int u2 = 0; u2 < 2; ++u2)
#pragma unroll
        for (int r = 0; r < 4; ++r)
            hd[(u2 * 16 + 4 * q + r) * 16] = (_Float16)h[u2][r];
}

// ---------------------------------------------------------------------------
// Kernel 2: FC1 partial GEMM, DMA-pipelined. Grid 256: block = K-chunk of
// 256 rows, processed as 4 chunks of 64 rows with double-buffered fp32 LDS
// (2 x 64 x 258 f32 = 132 KB) filled by global_load_lds (16 DMA instr/wave
// = 16 KB in flight/wave -> BW-saturated; R8's reg-staging held only 1 KB/CU
// in flight => 925 GB/s duty-cycle cap). Per chunk: A-frags loaded FIRST
// (so their vmcnt wait leaves the next chunk's DMA outstanding), then DMA
// for chunk c+1, then 32 MFMAs with B built from LDS (8 ds_read_b32 + cvt;
// stride 258 => 2-way bank alias only). One barrier per chunk. Partials
// written f16, no atomics.
// ---------------------------------------------------------------------------
__global__
__attribute__((amdgpu_flat_work_group_size(256, 256), amdgpu_waves_per_eu(1, 2)))
void fc1_mfma(const _Float16* __restrict__ h_t, const float* __restrict__ W1,
              _Float16* __restrict__ partials)
{
    __shared__ float w1s[2][64][258];         // 132096 B
    const int tid  = threadIdx.x;
    const int wave = tid >> 6;
    const int lane = tid & 63;
    const int t16  = lane & 15;
    const int q    = lane >> 4;
    const int i0   = blockIdx.x * 256;

    f32x4 acc[4][4];
#pragma unroll
    for (int mt = 0; mt < 4; ++mt)
#pragma unroll
        for (int nt = 0; nt < 4; ++nt)
            acc[mt][nt] = (f32x4){0.f, 0.f, 0.f, 0.f};

    // prologue: DMA chunk 0 (wave stages rows wave*16..wave*16+15; one
    // instruction copies one 1024B W1 row into LDS base+lane*16)
#pragma unroll
    for (int r = 0; r < 16; ++r) {
        int row = wave * 16 + r;
        load_lds16(W1 + (size_t)(i0 + row) * 256 + lane * 4, &w1s[0][row][0]);
    }
    __syncthreads();                           // drains chunk-0 DMA

#pragma unroll 1
    for (int c = 0; c < 4; ++c) {
        const int buf = c & 1;
        const int cb  = i0 + c * 64;

        // A-frags for this chunk, issued BEFORE next DMA so their vmcnt
        // wait does not drain the DMA queue
        half8_t A[2][4];
#pragma unroll
        for (int ks = 0; ks < 2; ++ks)
#pragma unroll
            for (int mt = 0; mt < 4; ++mt)
                A[ks][mt] = *(const half8_t*)(h_t
                    + (size_t)(mt * 16 + t16) * 65536 + cb + ks * 32 + q * 8);

        if (c < 3) {
#pragma unroll
            for (int r = 0; r < 16; ++r) {
                int row = wave * 16 + r;
                load_lds16(W1 + (size_t)(cb + 64 + row) * 256 + lane * 4,
                           &w1s[buf ^ 1][row][0]);
            }
        }

#pragma unroll
        for (int ks = 0; ks < 2; ++ks) {
#pragma unroll
            for (int nt = 0; nt < 4; ++nt) {
                int j = (wave * 4 + nt) * 16 + t16;
                half8_t Bf;
#pragma unroll
                for (int i = 0; i < 8; ++i)
                    Bf[i] = (_Float16)w1s[buf][ks * 32 + q * 8 + i][j];
#pragma unroll
                for (int mt = 0; mt < 4; ++mt)
                    acc[mt][nt] = MFMA16(A[ks][mt], Bf, acc[mt][nt]);
            }
        }
        __syncthreads();                       // sync + drain next-chunk DMA
    }

    _Float16* pb = partials + (size_t)blockIdx.x * 16384;
#pragma unroll
    for (int mt = 0; mt < 4; ++mt)
#pragma unroll
        for (int nt = 0; nt < 4; ++nt)
#pragma unroll
            for (int r = 0; r < 4; ++r)
                pb[(mt * 16 + 4 * q + r) * 256 + (wave * 4 + nt) * 16 + t16] =
                    (_Float16)acc[mt][nt][r];
}

// ---------------------------------------------------------------------------
// Kernel 3: fused partial-reduce + bias + tail MLP + softmax. (unchanged)
// ---------------------------------------------------------------------------
__global__ __launch_bounds__(256) void mlp_tail(
    const _Float16* __restrict__ partials, const float* __restrict__ b1,
    const float* __restrict__ W2, const float* __restrict__ b2,
    const float* __restrict__ W3, const float* __restrict__ b3,
    float* __restrict__ out)
{
    __shared__ float x1[256];
    __shared__ float x2[32];
    __shared__ float lg[2];
    const int b = blockIdx.x, j = threadIdx.x;

    const _Float16* p = partials + (size_t)b * 256 + j;
    float s0 = 0.f, s1 = 0.f, s2 = 0.f, s3 = 0.f;
#pragma unroll 8
    for (int k = 0; k < 256; k += 4) {
        s0 += (float)p[(size_t)(k + 0) * 16384];
        s1 += (float)p[(size_t)(k + 1) * 16384];
        s2 += (float)p[(size_t)(k + 2) * 16384];
        s3 += (float)p[(size_t)(k + 3) * 16384];
    }
    x1[j] = fmaxf(b1[j] + s0 + s1 + s2 + s3, 0.0f);
    __syncthreads();

    if (j < 32) {
        float s = b2[j];
#pragma unroll 8
        for (int k = 0; k < 256; ++k) s += x1[k] * W2[k * 32 + j];
        x2[j] = fmaxf(s, 0.0f);
    }
    __syncthreads();

    if (j < 2) {
        float s = b3[j];
#pragma unroll
        for (int k = 0; k < 32; ++k) s += x2[k] * W3[k * 2 + j];
        lg[j] = s;
    }
    __syncthreads();

    if (j == 0) {
        float mx = fmaxf(lg[0], lg[1]);
        float e0 = __expf(lg[0] - mx), e1 = __expf(lg[1] - mx);
        float inv = 1.0f / (e0 + e1);
        out[b * 2 + 0] = e0 * inv;
        out[b * 2 + 1] = e1 * inv;
    }
}

// ---------------------------------------------------------------------------
extern "C" void kernel_launch(void* const* d_in, const int* in_sizes, int n_in,
                              void* d_out, int out_size, void* d_ws, size_t ws_size,
                              hipStream_t stream) {
    const float* inputs = (const float*)d_in[0];
    const float* Wn = (const float*)d_in[1];
    const float* Wg = (const float*)d_in[2];
    const float* Ug = (const float*)d_in[3];
    const float* bg = (const float*)d_in[4];
    const float* Wc = (const float*)d_in[5];
    const float* Uc = (const float*)d_in[6];
    const float* bc = (const float*)d_in[7];
    const float* We = (const float*)d_in[8];
    const float* be = (const float*)d_in[9];
    const float* W1 = (const float*)d_in[10];
    const float* b1 = (const float*)d_in[11];
    const float* W2 = (const float*)d_in[12];
    const float* b2 = (const float*)d_in[13];
    const float* W3 = (const float*)d_in[14];
    const float* b3 = (const float*)d_in[15];
    float* out = (float*)d_out;

    // ws: h_t f16 [64][65536] = 8 MB; partials f16 [256][64][256] = 8 MB
    _Float16* h_t      = (_Float16*)d_ws;
    _Float16* partials = (_Float16*)((char*)d_ws + (size_t)64 * 65536 * 2);

    ugrnn_mfma<<<2048, 256, 0, stream>>>(inputs, Wn, Wg, Ug, bg, Wc, Uc, bc,
                                         We, be, h_t);
    fc1_mfma<<<256, 256, 0, stream>>>(h_t, W1, partials);
    mlp_tail<<<64, 256, 0, stream>>>(partials, b1, W2, b2, W3, b3, out);
}